// Round 7
// baseline (410.885 us; speedup 1.0000x reference)
//
#include <hip/hip_runtime.h>
#include <hip/hip_fp16.h>

#define BB 4
#define HH 192
#define WW 640
#define CC 32
#define SS 32
#define PXB 64            // pixels per block; 640 % 64 == 0
#define NWG (BB * HH * WW / PXB)   // 7680 blocks; divisible by 8 (XCD swizzle)
#define NWAVE 4           // waves per block; wave w owns steps [8w, 8w+8)
#define SPW 8             // steps per wave
#define MAXW 116          // tier-1 staged window bound (source px); alpha <= ~1.8
#define PLANE (MAXW + 1)  // 117
#define PW 5              // prefetch chunks per lane; tier-0 iff width4 <= PW*64 (80 px)

typedef _Float16 half2n __attribute__((ext_vector_type(2)));

#if defined(__has_builtin)
#if __has_builtin(__builtin_amdgcn_fdot2)
#define HAS_FDOT2 1
#endif
#endif

static __device__ __forceinline__ float fdot2_acc(__half2 a, __half2 b, float acc) {
#ifdef HAS_FDOT2
    return __builtin_amdgcn_fdot2(__builtin_bit_cast(half2n, a),
                                  __builtin_bit_cast(half2n, b), acc, false);
#else
    const float2 af = __half22float2(a);
    const float2 bf = __half22float2(b);
    return acc + af.x * bf.x + af.y * bf.y;
#endif
}

static __device__ __forceinline__ unsigned pk2(float w) {
    // half2(w, w) as a packed uint
    return (unsigned)__builtin_bit_cast(unsigned short, __float2half_rn(w)) * 0x10001u;
}

// Wave-local LDS fence: orders this wave's ds_writes before its later
// ds_reads at the compiler level ("memory" clobber + sched_barrier) and
// drains the DS queue (lgkmcnt 0). Replaces __syncthreads for buffers that
// only one wave touches — no cross-wave rendezvous cost.
static __device__ __forceinline__ void wave_lds_fence() {
    asm volatile("s_waitcnt lgkmcnt(0)" ::: "memory");
    __builtin_amdgcn_sched_barrier(0);
}

// x (fp32, 63MB) -> fp16 copy in workspace (31.5MB). Re-run every call.
__global__ __launch_bounds__(256) void convert_x_kernel(const float* __restrict__ x,
                                                        __half* __restrict__ xh) {
    const size_t i = ((size_t)blockIdx.x * 256 + threadIdx.x) * 8;
    const float4 f0 = *(const float4*)(x + i);
    const float4 f1 = *(const float4*)(x + i + 4);
    uint4 u;
    u.x = __builtin_bit_cast(unsigned, __floats2half2_rn(f0.x, f0.y));
    u.y = __builtin_bit_cast(unsigned, __floats2half2_rn(f0.z, f0.w));
    u.z = __builtin_bit_cast(unsigned, __floats2half2_rn(f1.x, f1.y));
    u.w = __builtin_bit_cast(unsigned, __floats2half2_rn(f1.z, f1.w));
    *(uint4*)(xh + i) = u;
}

// R14: decoupled multi-wave workgroups.
//  Evidence: 1-wave WGs cap at ~10-12 resident WGs/CU (R11/R13 occupancy
//  32-38% despite LDS headroom); R12's 2-wave WGs reached 60% but coupled
//  the waves with per-step barriers on a shared buffer (regressed).
//  This round: 4-wave blocks, wave w owns steps [8w, 8w+8) for the block's
//  64 pixels, staging into a WAVE-PRIVATE comb buffer. No __syncthreads in
//  the hot loop — stage->consume ordering within a wave is the in-order DS
//  pipe + an explicit wave_lds_fence (the fence R10 lacked when it NaN'd).
//  LDS = 4x(4x117x16) + 1KB = 31KB -> 5 blocks/CU = 20 waves/CU (~62%).
//  Also: consume dot-chain split into 4 independent accumulators (was a
//  16-deep serial fdot2 chain on the per-step critical path).
//  Kept from R13: T14 prefetch (tier 0), tier-1 serial stage, tier-2 gather,
//  XCD-aware bijective block swizzle (FETCH 296->119MB, proven).
__global__ __launch_bounds__(256, 4) void corr_kernel(
    const __half* __restrict__ xh, const float* __restrict__ y,
    const float* __restrict__ origin, const float* __restrict__ focal,
    const float* __restrict__ T12, float* __restrict__ out)
{
    // sU[s] = { alpha, dkx, xlo, width4 }   sV[s] = { r0byte, r1byte, wy0pk, wy1pk }
    __shared__ uint4 sU[SS];
    __shared__ uint4 sV[SS];
    __shared__ uint4 comb[NWAVE][4][PLANE];   // 29,952 B (wave-private slices)

    const int tid  = threadIdx.x;
    const int lane = tid & 63;
    const int wave = tid >> 6;

    // XCD swizzle: XCD k (= blockIdx.x & 7) covers a contiguous 960-block
    // range. Bijective since NWG % 8 == 0.
    const int bid = ((int)blockIdx.x & 7) * (NWG >> 3) + ((int)blockIdx.x >> 3);

    const int p0 = bid * PXB;
    const int w0 = p0 % WW;
    const int h  = (p0 / WW) % HH;
    const int b  = p0 / (WW * HH);

    // ---- per-step uniforms (threads 0..31, one step each; R9/R11-proven) ----
    if (tid < SS) {
        const float tz = T12[b * 3 + 2];
        const float kx = tz * origin[b * 2 + 0] + focal[b * 2 + 0] * T12[b * 3 + 0];
        const float ky = tz * origin[b * 2 + 1] + focal[b * 2 + 1] * T12[b * 3 + 1];
        const float sf = (float)tid;
        // D = s/(1+s*tz); s=0 -> D=0 automatically (matches reference).
        const float D = sf * __builtin_amdgcn_rcpf(1.0f + sf * tz);
        const float alpha = 1.0f - D * tz;
        const float dkx = D * kx;
        const float dky = D * ky;

        const float syv = alpha * (float)h + dky;
        const float y0f = floorf(syv);
        const float fy  = syv - y0f;
        const int   y0  = (int)y0f;
        const int   y1  = y0 + 1;
        const float wy0 = (y0 >= 0 && y0 < HH) ? (1.0f - fy) : 0.0f;
        const float wy1 = (y1 >= 0 && y1 < HH) ? fy : 0.0f;
        const int   cy0 = min(max(y0, 0), HH - 1);
        const int   cy1 = min(max(y1, 0), HH - 1);

        const float sxa = alpha * (float)w0 + dkx;
        const float sxb = alpha * (float)(w0 + PXB - 1) + dkx;
        const int xlo = (int)floorf(fminf(sxa, sxb));
        const int xhi = (int)floorf(fmaxf(sxa, sxb)) + 1;
        const int width4 = (xhi - xlo + 1) * 4;   // 16B chunks to stage

        uint4 U, V;
        U.x = __builtin_bit_cast(unsigned, alpha);
        U.y = __builtin_bit_cast(unsigned, dkx);
        U.z = (unsigned)xlo;
        U.w = (unsigned)width4;
        V.x = (unsigned)((cy0 * WW) << 6);   // row byte base in fp16 image
        V.y = (unsigned)((cy1 * WW) << 6);
        V.z = pk2(wy0);
        V.w = pk2(wy1);
        sU[tid] = U;
        sV[tid] = V;
    }

    const int pme = p0 + lane;
    // lane's 32 y channels as 16 half2 (coalesced; all 4 waves read the same
    // 8KB tile — extra L2 reads, no extra HBM).
    __half2 yh[16];
    {
        const float4* yp = (const float4*)(y + (size_t)pme * CC);
#pragma unroll
        for (int q = 0; q < 8; ++q) {
            const float4 f = yp[q];
            yh[2 * q]     = __floats2half2_rn(f.x, f.y);
            yh[2 * q + 1] = __floats2half2_rn(f.z, f.w);
        }
    }

    const char* xbase = (const char*)(xh + (size_t)b * HH * WW * CC);
    const float pxf = (float)(w0 + lane);

    __syncthreads();   // uniforms table ready (only cross-wave sync point)

    uint4 (* const myc)[PLANE] = comb[wave];   // wave-private staging buffer
    const int s0 = wave * SPW;

    // ---- prologue: stage this wave's first step serially ----
    uint4 U = sU[s0];
    uint4 V = sV[s0];
    {
        const int xlo    = (int)U.z;
        const int width4 = (int)U.w;
        if (width4 <= MAXW * 4) {
            const __half2 wy0h = __builtin_bit_cast(__half2, V.z);
            const __half2 wy1h = __builtin_bit_cast(__half2, V.w);
            for (int c = lane; c < width4; c += 64) {
                const int cpx = min(max(xlo + (c >> 2), 0), WW - 1);
                const unsigned po = (unsigned)((cpx << 6) + ((c & 3) << 4));
                const uint4 a  = *(const uint4*)(xbase + (size_t)(V.x + po));
                const uint4 bq = *(const uint4*)(xbase + (size_t)(V.y + po));
                uint4 o;
#pragma unroll
                for (int i = 0; i < 4; ++i) {
                    __half2 r = __hmul2(__builtin_bit_cast(__half2, (&a.x)[i]), wy0h);
                    r = __hfma2(__builtin_bit_cast(__half2, (&bq.x)[i]), wy1h, r);
                    (&o.x)[i] = __builtin_bit_cast(unsigned, r);
                }
                myc[c & 3][c >> 2] = o;
            }
        }
    }
    wave_lds_fence();   // stage(s0) ordered before consume(s0)

    float res[SPW];

#pragma unroll
    for (int j = 0; j < SPW; ++j) {
        const int s = s0 + j;
        const float alpha  = __builtin_bit_cast(float, U.x);
        const float dkx    = __builtin_bit_cast(float, U.y);
        const int   xlo    = (int)U.z;
        const int   width4 = (int)U.w;

        // ---- per-lane x interpolation params for step s ----
        const float sx  = alpha * pxf + dkx;
        const float x0f = floorf(sx);
        const float fx  = sx - x0f;
        const int   x0  = (int)x0f;
        const int   x1  = x0 + 1;
        const float wx0f = (x0 >= 0 && x0 < WW) ? (1.0f - fx) : 0.0f;
        const float wx1f = (x1 >= 0 && x1 < WW) ? fx : 0.0f;
        const __half2 wx0 = __builtin_bit_cast(__half2, pk2(wx0f));
        const __half2 wx1 = __builtin_bit_cast(__half2, pk2(wx1f));
        const int cx0 = min(max(x0, 0), WW - 1);
        const int cx1 = min(max(x1, 0), WW - 1);

        // ---- ISSUE: step s+1 staging loads into registers (tier 0) ----
        uint4 pa[PW], pb[PW];
        uint4 Un, Vn;
        int tn = 3, xlon = 0, width4n = 0;
        if (j + 1 < SPW) {
            Un = sU[s + 1];
            Vn = sV[s + 1];
            xlon    = (int)Un.z;
            width4n = (int)Un.w;
            tn = (width4n <= PW * 64) ? 0 : ((width4n <= MAXW * 4) ? 1 : 2);
            if (tn == 0) {
#pragma unroll
                for (int i = 0; i < PW; ++i) {
                    const int c  = lane + i * 64;
                    const int cc = min(c, width4n - 1);        // clamp (masked on store)
                    const int cpx = min(max(xlon + (cc >> 2), 0), WW - 1);
                    const unsigned po = (unsigned)((cpx << 6) + ((cc & 3) << 4));
                    pa[i] = *(const uint4*)(xbase + (size_t)(Vn.x + po));
                    pb[i] = *(const uint4*)(xbase + (size_t)(Vn.y + po));
                }
            }
        }

        // ---- CONSUME step s (overlaps the loads above) ----
        float ac0 = 0.0f, ac1 = 0.0f, ac2 = 0.0f, ac3 = 0.0f;
        if (width4 <= MAXW * 4) {
            const int wlim = (width4 >> 2) - 1;
            const int l0 = min(max(cx0 - xlo, 0), wlim);
            const int l1 = min(max(cx1 - xlo, 0), wlim);
            const uint4* b0 = &myc[0][l0];
            const uint4* b1 = &myc[0][l1];
            uint4 A[4], Bq[4];
#pragma unroll
            for (int i = 0; i < 4; ++i) {
                A[i]  = b0[i * PLANE];          // imm offsets i*1872
                Bq[i] = b1[i * PLANE];
            }
#pragma unroll
            for (int i = 0; i < 4; ++i) {
                __half2 v0 = __hmul2(__builtin_bit_cast(__half2, A[i].x), wx0);
                v0 = __hfma2(__builtin_bit_cast(__half2, Bq[i].x), wx1, v0);
                ac0 = fdot2_acc(v0, yh[i * 4 + 0], ac0);
                __half2 v1 = __hmul2(__builtin_bit_cast(__half2, A[i].y), wx0);
                v1 = __hfma2(__builtin_bit_cast(__half2, Bq[i].y), wx1, v1);
                ac1 = fdot2_acc(v1, yh[i * 4 + 1], ac1);
                __half2 v2 = __hmul2(__builtin_bit_cast(__half2, A[i].z), wx0);
                v2 = __hfma2(__builtin_bit_cast(__half2, Bq[i].z), wx1, v2);
                ac2 = fdot2_acc(v2, yh[i * 4 + 2], ac2);
                __half2 v3 = __hmul2(__builtin_bit_cast(__half2, A[i].w), wx0);
                v3 = __hfma2(__builtin_bit_cast(__half2, Bq[i].w), wx1, v3);
                ac3 = fdot2_acc(v3, yh[i * 4 + 3], ac3);
            }
        } else {
            // gather fallback (window too wide for LDS) — R11-proven
            const __half2 wy0h = __builtin_bit_cast(__half2, V.z);
            const __half2 wy1h = __builtin_bit_cast(__half2, V.w);
            const uint4* r0p0 = (const uint4*)(xbase + (size_t)(V.x + ((unsigned)cx0 << 6)));
            const uint4* r0p1 = (const uint4*)(xbase + (size_t)(V.x + ((unsigned)cx1 << 6)));
            const uint4* r1p0 = (const uint4*)(xbase + (size_t)(V.y + ((unsigned)cx0 << 6)));
            const uint4* r1p1 = (const uint4*)(xbase + (size_t)(V.y + ((unsigned)cx1 << 6)));
#pragma unroll
            for (int i = 0; i < 4; ++i) {
                const uint4 a  = r0p0[i];
                const uint4 bq = r0p1[i];
                const uint4 c2 = r1p0[i];
                const uint4 d  = r1p1[i];
#pragma unroll
                for (int w = 0; w < 4; ++w) {
                    __half2 top = __hmul2(__builtin_bit_cast(__half2, (&a.x)[w]), wx0);
                    top = __hfma2(__builtin_bit_cast(__half2, (&bq.x)[w]), wx1, top);
                    __half2 bot = __hmul2(__builtin_bit_cast(__half2, (&c2.x)[w]), wx0);
                    bot = __hfma2(__builtin_bit_cast(__half2, (&d.x)[w]), wx1, bot);
                    __half2 v = __hmul2(top, wy0h);
                    v = __hfma2(bot, wy1h, v);
                    if (w == 0)      ac0 = fdot2_acc(v, yh[i * 4 + 0], ac0);
                    else if (w == 1) ac1 = fdot2_acc(v, yh[i * 4 + 1], ac1);
                    else if (w == 2) ac2 = fdot2_acc(v, yh[i * 4 + 2], ac2);
                    else             ac3 = fdot2_acc(v, yh[i * 4 + 3], ac3);
                }
            }
        }
        const float acc = (ac0 + ac1) + (ac2 + ac3);

        // ---- STAGE step s+1 into the wave-private buffer (write-late) ----
        if (j + 1 < SPW) {
            if (tn == 0) {
                const __half2 wy0h = __builtin_bit_cast(__half2, Vn.z);
                const __half2 wy1h = __builtin_bit_cast(__half2, Vn.w);
#pragma unroll
                for (int i = 0; i < PW; ++i) {
                    const int c = lane + i * 64;
                    if (c < width4n) {
                        uint4 o;
#pragma unroll
                        for (int q = 0; q < 4; ++q) {
                            __half2 r = __hmul2(__builtin_bit_cast(__half2, (&pa[i].x)[q]), wy0h);
                            r = __hfma2(__builtin_bit_cast(__half2, (&pb[i].x)[q]), wy1h, r);
                            (&o.x)[q] = __builtin_bit_cast(unsigned, r);
                        }
                        myc[c & 3][c >> 2] = o;
                    }
                }
            } else if (tn == 1) {
                const __half2 wy0h = __builtin_bit_cast(__half2, Vn.z);
                const __half2 wy1h = __builtin_bit_cast(__half2, Vn.w);
                for (int c = lane; c < width4n; c += 64) {
                    const int cpx = min(max(xlon + (c >> 2), 0), WW - 1);
                    const unsigned po = (unsigned)((cpx << 6) + ((c & 3) << 4));
                    const uint4 a  = *(const uint4*)(xbase + (size_t)(Vn.x + po));
                    const uint4 bq = *(const uint4*)(xbase + (size_t)(Vn.y + po));
                    uint4 o;
#pragma unroll
                    for (int q = 0; q < 4; ++q) {
                        __half2 r = __hmul2(__builtin_bit_cast(__half2, (&a.x)[q]), wy0h);
                        r = __hfma2(__builtin_bit_cast(__half2, (&bq.x)[q]), wy1h, r);
                        (&o.x)[q] = __builtin_bit_cast(unsigned, r);
                    }
                    myc[c & 3][c >> 2] = o;
                }
            }
            // tn==2: step s+1 gathers from global; nothing staged.
            wave_lds_fence();   // stage(s+1) ordered before consume(s+1)
            U = Un;
            V = Vn;
        }

        res[j] = acc * (1.0f / 32.0f);
    }

    // 32B sector-aligned store of this wave's 8 steps for this lane's pixel.
    float* outp = out + (size_t)pme * SS + s0;
    *(float4*)(outp)     = make_float4(res[0], res[1], res[2], res[3]);
    *(float4*)(outp + 4) = make_float4(res[4], res[5], res[6], res[7]);
}

extern "C" void kernel_launch(void* const* d_in, const int* in_sizes, int n_in,
                              void* d_out, int out_size, void* d_ws, size_t ws_size,
                              hipStream_t stream) {
    const float* x = (const float*)d_in[0];
    const float* y = (const float*)d_in[1];
    const float* origin = (const float*)d_in[2];
    const float* focal = (const float*)d_in[3];
    const float* T12 = (const float*)d_in[4];
    float* out = (float*)d_out;
    __half* xh = (__half*)d_ws;   // needs BB*HH*WW*CC*2 = 31.5 MB

    const int nelem = BB * HH * WW * CC;          // 15,728,640
    convert_x_kernel<<<nelem / (256 * 8), 256, 0, stream>>>(x, xh);

    corr_kernel<<<NWG, 256, 0, stream>>>(xh, y, origin, focal, T12, out);
}

// Round 8
// 315.220 us; speedup vs baseline: 1.3035x; 1.3035x over previous
//
#include <hip/hip_runtime.h>
#include <hip/hip_fp16.h>

#define BB 4
#define HH 192
#define WW 640
#define CC 32
#define SS 32
#define PXB 64   // pixels per block (one row segment; 640 % 64 == 0)
#define SPH 8    // steps per phase (4 phases x 8 = 32)
#define NWG (BB * HH * WW / PXB)   // 7680 blocks; divisible by 8 (XCD swizzle)

typedef _Float16 half2n __attribute__((ext_vector_type(2)));

#if defined(__has_builtin)
#if __has_builtin(__builtin_amdgcn_fdot2)
#define HAS_FDOT2 1
#endif
#endif

// x (fp32, 63MB) -> fp16 copy in workspace (31.5MB). Re-run every call.
__global__ __launch_bounds__(256) void convert_x_kernel(const float* __restrict__ x,
                                                        __half* __restrict__ xh) {
    const size_t i = ((size_t)blockIdx.x * 256 + threadIdx.x) * 8;
    const float4 f0 = *(const float4*)(x + i);
    const float4 f1 = *(const float4*)(x + i + 4);
    uint4 u;
    u.x = __builtin_bit_cast(unsigned, __floats2half2_rn(f0.x, f0.y));
    u.y = __builtin_bit_cast(unsigned, __floats2half2_rn(f0.z, f0.w));
    u.z = __builtin_bit_cast(unsigned, __floats2half2_rn(f1.x, f1.y));
    u.w = __builtin_bit_cast(unsigned, __floats2half2_rn(f1.z, f1.w));
    *(uint4*)(xh + i) = u;
}

// R15 = R7 (best proven: 178us, occ 72%, VALU 40%, 0 LDS conflicts) + XCD
// swizzle, nothing else.
//  Post-mortem R8-R14: every staging variant (190-293us) lost to R7's
//  gather — R7's limiter is vector-memory ADDRESS throughput + miss
//  latency, amortized by 23 resident waves and zero hot-loop sync; staging
//  cut addresses but paid more in occupancy/serialization.
//  The one proven-portable win: XCD-aware bijective block swizzle (R13
//  same-structure A/B: FETCH 296->119MB). R7 fetches 180MB = 5.7x the
//  31.5MB fp16 image from cross-XCD row re-reads; giving each XCD a
//  contiguous 960-block (~96-row) range turns those into local-L2 hits
//  (~200cy vs ~900cy), which the resident waves hide far better.
// Wave = 16 pixel-slots x 4 channel-lanes (8 fp16 channels each).
// R7: R5's 2-deep corner-load pipeline (40 VGPR schedule) at (256,7).
__global__ __launch_bounds__(256, 7) void corr_kernel(
    const __half* __restrict__ xh, const float* __restrict__ y,
    const float* __restrict__ origin, const float* __restrict__ focal,
    const float* __restrict__ T12, float* __restrict__ out)
{
    __shared__ uint4 sOff[SPH * PXB];  // 4 corner byte-offsets
    __shared__ uint4 sWt [SPH * PXB];  // 4 corner weights, each packed half2(w,w)

    const int tid  = threadIdx.x;
    const int lane = tid & 63;
    const int wave = tid >> 6;
    const int slot = lane >> 2;   // pixel within wave (0..15)
    const int cg   = lane & 3;    // channel group: fp16 channels [8cg, 8cg+8)

    // XCD swizzle: XCD k (= blockIdx.x & 7) covers the contiguous block
    // range [k*960, (k+1)*960). Bijective since NWG % 8 == 0.
    const int bid = ((int)blockIdx.x & 7) * (NWG >> 3) + ((int)blockIdx.x >> 3);

    const int p0 = bid * PXB;
    const int w0 = p0 % WW;
    const int h  = (p0 / WW) % HH;
    const int b  = p0 / (WW * HH);

    const float tz = T12[b * 3 + 2];
    const float kx = tz * origin[b * 2 + 0] + focal[b * 2 + 0] * T12[b * 3 + 0];
    const float ky = tz * origin[b * 2 + 1] + focal[b * 2 + 1] * T12[b * 3 + 1];

    const int pme = p0 + wave * 16 + slot;
    // This lane's 8 y channels as 4 x half2
    __half2 yh[4];
    {
        const float4 ya = *(const float4*)(y + (size_t)pme * CC + cg * 8);
        const float4 yb = *(const float4*)(y + (size_t)pme * CC + cg * 8 + 4);
        yh[0] = __floats2half2_rn(ya.x, ya.y);
        yh[1] = __floats2half2_rn(ya.z, ya.w);
        yh[2] = __floats2half2_rn(yb.x, yb.y);
        yh[3] = __floats2half2_rn(yb.z, yb.w);
    }

    const char* xbase = (const char*)(xh + (size_t)b * HH * WW * CC);
    const int cgb = cg * 16;   // byte offset of channel group within 64B pixel
    const int sp  = wave * 16 + slot;

    // Phase-1 ownership: thread owns (e_px = tid&63, s_loc = tid>>6 and +4)
    const int e_px = tid & 63;
    const int e_s0 = tid >> 6;
    const float ewf = (float)(w0 + e_px);
    const float ehf = (float)h;

    float* outp = out + (size_t)pme * SS;

#pragma unroll 1
    for (int ph = 0; ph < 4; ++ph) {
        __syncthreads();
#pragma unroll
        for (int k = 0; k < 2; ++k) {
            const int s_loc = e_s0 + k * 4;
            const int s = ph * SPH + s_loc;
            const float sf = (float)s;
            // D = 1/(1/s + tz) = s/(1+s*tz); s=0 -> D=0 automatically.
            const float D = sf * __builtin_amdgcn_rcpf(1.0f + sf * tz);
            const float alpha = 1.0f - D * tz;
            const float sx = alpha * ewf + D * kx;
            const float sy = alpha * ehf + D * ky;

            const float x0f = floorf(sx);
            const float y0f = floorf(sy);
            const float fx = sx - x0f;
            const float fy = sy - y0f;
            const int x0 = (int)x0f;
            const int y0 = (int)y0f;
            const int x1 = x0 + 1;
            const int y1 = y0 + 1;

            const float wx0 = (x0 >= 0 && x0 < WW) ? (1.0f - fx) : 0.0f;
            const float wx1 = (x1 >= 0 && x1 < WW) ? fx : 0.0f;
            const float wy0 = (y0 >= 0 && y0 < HH) ? (1.0f - fy) : 0.0f;
            const float wy1 = (y1 >= 0 && y1 < HH) ? fy : 0.0f;

            const int cx0 = min(max(x0, 0), WW - 1);
            const int cx1 = min(max(x1, 0), WW - 1);
            const int cy0 = min(max(y0, 0), HH - 1);
            const int cy1 = min(max(y1, 0), HH - 1);

            const int r0 = cy0 * WW;
            const int r1 = cy1 * WW;
            // fp16 pixel record = 64B -> byte offset = (row*W+col) << 6
            const uint4 offs = make_uint4((unsigned)((r0 + cx0) << 6),
                                          (unsigned)((r0 + cx1) << 6),
                                          (unsigned)((r1 + cx0) << 6),
                                          (unsigned)((r1 + cx1) << 6));
            auto pk = [](float wgt) -> unsigned {
                const unsigned short us =
                    __builtin_bit_cast(unsigned short, __float2half_rn(wgt));
                return (unsigned)us * 0x10001u;   // half2(w, w)
            };
            const uint4 wts = make_uint4(pk(wy0 * wx0), pk(wy0 * wx1),
                                         pk(wy1 * wx0), pk(wy1 * wx1));
            sOff[s_loc * PXB + e_px] = offs;
            sWt [s_loc * PXB + e_px] = wts;
        }
        __syncthreads();

        float res0 = 0.0f, res1 = 0.0f;

        // ---- software pipeline: prologue (step 0 of this phase) ----
        uint4 o  = sOff[sp];
        uint4 wt = sWt [sp];
        uint4 ua = *(const uint4*)(xbase + (size_t)(o.x + cgb));
        uint4 ub = *(const uint4*)(xbase + (size_t)(o.y + cgb));
        uint4 uc = *(const uint4*)(xbase + (size_t)(o.z + cgb));
        uint4 ud = *(const uint4*)(xbase + (size_t)(o.w + cgb));

#pragma unroll
        for (int j = 0; j < SPH; ++j) {
            uint4 o2, wt2, na, nb, nc, nd;
            if (j + 1 < SPH) {
                // issue next step's loads BEFORE consuming current registers
                o2  = sOff[(j + 1) * PXB + sp];
                wt2 = sWt [(j + 1) * PXB + sp];
                na = *(const uint4*)(xbase + (size_t)(o2.x + cgb));
                nb = *(const uint4*)(xbase + (size_t)(o2.y + cgb));
                nc = *(const uint4*)(xbase + (size_t)(o2.z + cgb));
                nd = *(const uint4*)(xbase + (size_t)(o2.w + cgb));
            }

            const __half2 w00 = __builtin_bit_cast(__half2, wt.x);
            const __half2 w01 = __builtin_bit_cast(__half2, wt.y);
            const __half2 w10 = __builtin_bit_cast(__half2, wt.z);
            const __half2 w11 = __builtin_bit_cast(__half2, wt.w);

            float acc = 0.0f;
#pragma unroll
            for (int i = 0; i < 4; ++i) {
                const unsigned va = (&ua.x)[i];
                const unsigned vb = (&ub.x)[i];
                const unsigned vc = (&uc.x)[i];
                const unsigned vd = (&ud.x)[i];
                __half2 comb = __hmul2(__builtin_bit_cast(__half2, va), w00);
                comb = __hfma2(__builtin_bit_cast(__half2, vb), w01, comb);
                comb = __hfma2(__builtin_bit_cast(__half2, vc), w10, comb);
                comb = __hfma2(__builtin_bit_cast(__half2, vd), w11, comb);
#ifdef HAS_FDOT2
                acc = __builtin_amdgcn_fdot2(__builtin_bit_cast(half2n, comb),
                                             __builtin_bit_cast(half2n, yh[i]),
                                             acc, false);
#else
                const float2 cf = __half22float2(comb);
                const float2 yf = __half22float2(yh[i]);
                acc += cf.x * yf.x + cf.y * yf.y;
#endif
            }

            // Reduce over the 4 channel-lanes (hardware quad -> DPP quad_perm).
            acc += __shfl_xor(acc, 1, 64);
            acc += __shfl_xor(acc, 2, 64);

            if ((j & 3) == cg) {
                if (j < 4) res0 = acc * (1.0f / 32.0f);
                else       res1 = acc * (1.0f / 32.0f);
            }

            if (j + 1 < SPH) {  // rotate pipeline registers (SSA under unroll)
                o = o2; wt = wt2; ua = na; ub = nb; uc = nc; ud = nd;
            }
        }
        outp[ph * SPH + cg]     = res0;
        outp[ph * SPH + 4 + cg] = res1;
    }
}

extern "C" void kernel_launch(void* const* d_in, const int* in_sizes, int n_in,
                              void* d_out, int out_size, void* d_ws, size_t ws_size,
                              hipStream_t stream) {
    const float* x = (const float*)d_in[0];
    const float* y = (const float*)d_in[1];
    const float* origin = (const float*)d_in[2];
    const float* focal = (const float*)d_in[3];
    const float* T12 = (const float*)d_in[4];
    float* out = (float*)d_out;
    __half* xh = (__half*)d_ws;   // needs BB*HH*WW*CC*2 = 31.5 MB

    const int nelem = BB * HH * WW * CC;          // 15,728,640
    convert_x_kernel<<<nelem / (256 * 8), 256, 0, stream>>>(x, xh);

    corr_kernel<<<NWG, 256, 0, stream>>>(xh, y, origin, focal, T12, out);
}